// Round 4
// baseline (56.392 us; speedup 1.0000x reference)
//
#include <hip/hip_runtime.h>

// Problem constants (from reference)
#define B_    16
#define N_    25200
#define NC_   80
#define NM_   32
#define NDET_ 100
#define H_    160
#define W_    160
#define HW_   (H_ * W_)
#define XDIM_ (5 + NC_ + NM_)   // 117
#define COEF_OFF_ (5 + NC_)     // 85

// Output layout (flat f32):
#define OFF_BOXES_   16
#define OFF_SCORES_  6416
#define OFF_CLASSES_ 8016
#define OFF_MASKS_   9616

#define OCHUNK_ 50              // detections per grid.z slice (2 slices)

typedef float f32x4 __attribute__((ext_vector_type(4)));

// Single fused kernel. Grid: (HW/256 = 100 tiles, B = 16, 2 o-chunks) = 3200 blocks
// = 12800 waves (~8 waves/SIMD resident). 1 px/thread; all per-detection data is
// wave-uniform -> scalar loads; 2-way manual unroll batches the uniform loads.
__global__ __launch_bounds__(256) void mask_kernel(
    const float* __restrict__ x0,
    const float* __restrict__ proto,
    const int*   __restrict__ num_det,
    const float* __restrict__ det_boxes,
    const float* __restrict__ det_scores,
    const int*   __restrict__ det_classes,
    const int*   __restrict__ det_indices,
    float* __restrict__ out)
{
    const int b    = blockIdx.y;
    const int tile = blockIdx.x;
    const int oz   = blockIdx.z;
    const int tid  = threadIdx.x;

    // Fused head outputs (one block per batch does the small copies).
    if (oz == 0 && tile == 0) {
        if (tid == 0) out[b] = (float)num_det[b];
        for (int i = tid; i < NDET_ * 4; i += 256)
            out[OFF_BOXES_ + b * NDET_ * 4 + i] = det_boxes[b * NDET_ * 4 + i];
        for (int i = tid; i < NDET_; i += 256) {
            out[OFF_SCORES_  + b * NDET_ + i] = det_scores[b * NDET_ + i];
            out[OFF_CLASSES_ + b * NDET_ + i] = (float)det_classes[b * NDET_ + i];
        }
    }

    const int p = tile * 256 + tid;
    const float rf = (float)(p % W_);
    const float cf = (float)(p / W_);

    // This pixel's proto column (32 values) in registers, coalesced loads.
    const float* __restrict__ pp = proto + (size_t)b * NM_ * HW_ + p;
    float pr[NM_];
#pragma unroll
    for (int m = 0; m < NM_; ++m) pr[m] = pp[(size_t)m * HW_];

    const f32x4* __restrict__ sbox = (const f32x4*)det_boxes + b * NDET_ + oz * OCHUNK_;
    const int*   __restrict__ dind = det_indices + b * NDET_ + oz * OCHUNK_;

    float* __restrict__ outp =
        out + OFF_MASKS_ + ((size_t)b * NDET_ + oz * OCHUNK_) * HW_ + p;

    for (int o = 0; o < OCHUNK_; o += 2) {
        // Batched wave-uniform loads for two detections (issue together, wait once).
        const f32x4 bxa = sbox[o]     * 0.25f;
        const f32x4 bxb = sbox[o + 1] * 0.25f;
        const int   ia  = dind[o];
        const int   ib  = dind[o + 1];

        const bool ina = (rf >= bxa.x) & (rf < bxa.z) & (cf >= bxa.y) & (cf < bxa.w);
        const bool inb = (rf >= bxb.x) & (rf < bxb.z) & (cf >= bxb.y) & (cf < bxb.w);

        float va = 0.0f, vb = 0.0f;
        if (__ballot(ina) != 0) {
            const float* __restrict__ cfp =
                x0 + ((size_t)b * N_ + ia) * XDIM_ + COEF_OFF_;   // uniform -> s_load
            float acc = 0.0f;
#pragma unroll
            for (int m = 0; m < NM_; ++m) acc += cfp[m] * pr[m];
            const float s = 1.0f / (1.0f + __expf(-acc));
            va = ina ? s : 0.0f;
        }
        if (__ballot(inb) != 0) {
            const float* __restrict__ cfp =
                x0 + ((size_t)b * N_ + ib) * XDIM_ + COEF_OFF_;
            float acc = 0.0f;
#pragma unroll
            for (int m = 0; m < NM_; ++m) acc += cfp[m] * pr[m];
            const float s = 1.0f / (1.0f + __expf(-acc));
            vb = inb ? s : 0.0f;
        }
        __builtin_nontemporal_store(va, outp + (size_t)(o)     * HW_);
        __builtin_nontemporal_store(vb, outp + (size_t)(o + 1) * HW_);
    }
}

extern "C" void kernel_launch(void* const* d_in, const int* in_sizes, int n_in,
                              void* d_out, int out_size, void* d_ws, size_t ws_size,
                              hipStream_t stream)
{
    const float* x0          = (const float*)d_in[0];
    const float* proto       = (const float*)d_in[1];
    const int*   num_det     = (const int*)  d_in[2];
    const float* det_boxes   = (const float*)d_in[3];
    const float* det_scores  = (const float*)d_in[4];
    const int*   det_classes = (const int*)  d_in[5];
    const int*   det_indices = (const int*)  d_in[6];
    float* out = (float*)d_out;

    dim3 grid(HW_ / 256, B_, 2);
    mask_kernel<<<grid, 256, 0, stream>>>(
        x0, proto, num_det, det_boxes, det_scores, det_classes, det_indices, out);
}